// Round 1
// baseline (5380.294 us; speedup 1.0000x reference)
//
#include <hip/hip_runtime.h>
#include <hip/hip_bf16.h>

#define B_ 8
#define T_ 256
#define N_ 32
#define D_ 128
#define S_ 8
#define V_ 32000
#define H_ 4
#define HD_ 32
#define NCHUNK 32
#define CH_ 8

__device__ __forceinline__ float gelu_f(float x){
    return 0.5f * x * (1.0f + erff(x * 0.70710678118654752440f));
}
__device__ __forceinline__ float sigm(float x){
    return 1.0f / (1.0f + expf(-x));
}

// -------------------- percepts = LN(gelu(raw @ ifc_w + b)) --------------------
__global__ void k_percepts(const int* __restrict__ idx, const float* __restrict__ emb,
                           const float* __restrict__ pos_emb, const float* __restrict__ ifc_w,
                           const float* __restrict__ ifc_b, const float* __restrict__ ifc_g,
                           const float* __restrict__ ifc_beta, float* __restrict__ percepts){
    int r = blockIdx.x;          // r = b*T + t
    int t = r % T_;
    int d = threadIdx.x;         // 128 threads
    __shared__ float raw[D_];
    __shared__ float red[D_];
    int tok = idx[r];
    raw[d] = emb[tok*D_ + d] + pos_emb[t*D_ + d];
    __syncthreads();
    float acc = ifc_b[d];
    #pragma unroll 8
    for (int k=0;k<D_;k++) acc += raw[k]*ifc_w[k*D_+d];
    float x = gelu_f(acc);
    red[d] = x; __syncthreads();
    for (int s=64;s>0;s>>=1){ if(d<s) red[d]+=red[d+s]; __syncthreads(); }
    float m = red[0]*(1.0f/D_); __syncthreads();
    float dv = x-m; red[d] = dv*dv; __syncthreads();
    for (int s=64;s>0;s>>=1){ if(d<s) red[d]+=red[d+s]; __syncthreads(); }
    float var = red[0]*(1.0f/D_);
    percepts[r*D_ + d] = dv * (1.0f/sqrtf(var + 1e-5f)) * ifc_g[d] + ifc_beta[d];
}

// ------ hoisted precompute: sensory, sgate-sensory-part, residual->out contribution ------
__global__ void __launch_bounds__(256) k_precomp(const float* __restrict__ percepts,
                          const float* __restrict__ sproj_w, const float* __restrict__ sproj_b,
                          const float* __restrict__ sgate_w,
                          const float* __restrict__ res_w, const float* __restrict__ res_b,
                          const float* __restrict__ out_w,
                          float* __restrict__ sensory, float* __restrict__ sg_sens,
                          float* __restrict__ outres){
    int blk = blockIdx.x;     // 256: b*32 + c
    int b = blk >> 5, c = blk & 31;
    int tid = threadIdx.x;    // 256
    __shared__ float p[CH_][D_];
    __shared__ float sens[CH_][S_*D_];
    __shared__ float resid[CH_][D_];
    int tbase = b*T_ + c*CH_;
    for (int i = tid; i < CH_*D_; i += 256) p[i>>7][i&127] = percepts[(tbase + (i>>7))*D_ + (i&127)];
    __syncthreads();
    // sensory: 1024 output cols, 4 per thread, 8 t-rows each
    for (int q=0;q<4;q++){
        int sd = tid + 256*q;
        float acc[CH_];
        #pragma unroll
        for(int i=0;i<CH_;i++) acc[i] = sproj_b[sd];
        for (int k=0;k<D_;k++){
            float w = sproj_w[k*(S_*D_) + sd];
            #pragma unroll
            for(int i=0;i<CH_;i++) acc[i] += p[i][k]*w;
        }
        #pragma unroll
        for(int i=0;i<CH_;i++){
            sens[i][sd] = acc[i];
            sensory[(size_t)(tbase+i)*(S_*D_) + sd] = acc[i];
        }
    }
    __syncthreads();
    // sg_sens[i][s][d] = sum_k sens[i][s*128+k] * sgate_w[128+k][d]
    {
        int d = tid & 127, h = tid >> 7;   // h: i-half
        float acc[4][S_];
        #pragma unroll
        for(int ii=0;ii<4;ii++)
            #pragma unroll
            for(int s=0;s<S_;s++) acc[ii][s]=0.f;
        for (int k=0;k<D_;k++){
            float w = sgate_w[(D_+k)*D_ + d];
            #pragma unroll
            for(int ii=0;ii<4;ii++){
                int i = h*4+ii;
                #pragma unroll
                for(int s=0;s<S_;s++) acc[ii][s] += sens[i][s*D_+k]*w;
            }
        }
        for(int ii=0;ii<4;ii++){ int i=h*4+ii;
            for(int s=0;s<S_;s++) sg_sens[((size_t)(tbase+i)*S_+s)*D_ + d] = acc[ii][s];
        }
    }
    __syncthreads();
    // residual
    {
        int d = tid & 127, h = tid>>7;
        float acc[4];
        #pragma unroll
        for(int ii=0;ii<4;ii++) acc[ii]=res_b[d];
        for(int k=0;k<D_;k++){
            float w = res_w[k*D_+d];
            #pragma unroll
            for(int ii=0;ii<4;ii++) acc[ii] += p[h*4+ii][k]*w;
        }
        for(int ii=0;ii<4;ii++) resid[h*4+ii][d]=acc[ii];
    }
    __syncthreads();
    // outres = residual @ out_w[128:256]
    {
        int d = tid & 127, h = tid>>7;
        float acc[4];
        #pragma unroll
        for(int ii=0;ii<4;ii++) acc[ii]=0.f;
        for(int k=0;k<D_;k++){
            float w = out_w[(D_+k)*D_ + d];
            #pragma unroll
            for(int ii=0;ii<4;ii++) acc[ii] += resid[h*4+ii][k]*w;
        }
        for(int ii=0;ii<4;ii++) outres[(size_t)(tbase+h*4+ii)*D_ + d] = acc[ii];
    }
}

// -------------------- per-chunk timestep scan, one block per b --------------------
__global__ void __launch_bounds__(1024) k_scan(int c,
        const float* __restrict__ sensory, const float* __restrict__ sg_sens,
        const float* __restrict__ sgate_w, const float* __restrict__ sgate_b,
        const float* __restrict__ sal_w, const float* __restrict__ sal_b,
        const float* __restrict__ out_w, const float* __restrict__ out_b,
        const float* __restrict__ outres,
        const float* __restrict__ bcast_w, const float* __restrict__ bcast_b,
        const float* __restrict__ wln_g, const float* __restrict__ wln_b,
        float* __restrict__ states, float* __restrict__ bcast, float* __restrict__ proj){
    int b = blockIdx.x;
    int tid = threadIdx.x;
    __shared__ float st[N_*D_];
    __shared__ float ns[S_*D_];
    __shared__ float salv[N_], wtsv[N_], wsv[D_];
    __shared__ float red[D_];
    for (int i=tid;i<N_*D_;i+=1024) st[i] = states[b*N_*D_+i];
    __syncthreads();
    int s = tid >> 7, d = tid & 127;
    for (int step=0; step<CH_; step++){
        int tg = b*T_ + c*CH_ + step;
        // sgate state-part + precomputed sensory part
        float acc = sg_sens[((size_t)tg*S_+s)*D_+d] + sgate_b[d];
        const float* stp = &st[s*D_];
        #pragma unroll 8
        for (int k=0;k<D_;k++) acc += stp[k]*sgate_w[k*D_+d];
        float sg = sigm(acc);
        float sv = sensory[((size_t)tg*S_+s)*D_+d];
        ns[tid] = sg*stp[d] + (1.0f-sg)*sv;
        __syncthreads();
        st[tid] = ns[tid];
        __syncthreads();
        // sal over all 32 nodes
        if (tid < 512){
            int nn = tid >> 4, l = tid & 15;
            float pa = 0.f;
            #pragma unroll
            for (int j=0;j<8;j++) pa += st[nn*D_ + l + 16*j]*sal_w[l+16*j];
            #pragma unroll
            for (int off=8;off;off>>=1) pa += __shfl_down(pa, off, 16);
            if (l==0) salv[nn] = pa + sal_b[0];
        }
        __syncthreads();
        // softmax(sal*5) on wave 0
        if (tid < 64){
            float v = (tid<N_)? salv[tid]*5.0f : -1e30f;
            float m = v;
            #pragma unroll
            for (int off=32;off;off>>=1) m = fmaxf(m, __shfl_xor(m, off, 64));
            float e = (tid<N_)? expf(v-m) : 0.f;
            float Z = e;
            #pragma unroll
            for (int off=32;off;off>>=1) Z += __shfl_xor(Z, off, 64);
            if (tid<N_) wtsv[tid] = e/Z;
        }
        __syncthreads();
        if (tid < D_){
            float w = 0.f;
            #pragma unroll 4
            for (int n=0;n<N_;n++) w += wtsv[n]*st[n*D_+tid];
            wsv[tid] = w;
        }
        __syncthreads();
        if (tid < D_){
            float a2 = out_b[tid] + outres[(size_t)tg*D_+tid];
            #pragma unroll 8
            for (int k=0;k<D_;k++) a2 += wsv[k]*out_w[k*D_+tid];
            proj[(size_t)tg*D_+tid] = gelu_f(a2);
        }
        if (step==CH_-1){
            // bcast = LN(workspace @ bcast_w + b) -- only last step's value is carried
            float a3 = 0.f;
            if (tid<D_){
                a3 = bcast_b[tid];
                #pragma unroll 8
                for (int k=0;k<D_;k++) a3 += wsv[k]*bcast_w[k*D_+tid];
                red[tid] = a3;
            }
            __syncthreads();
            for (int sh=64;sh;sh>>=1){ if(tid<sh) red[tid]+=red[tid+sh]; __syncthreads(); }
            float mb = red[0]*(1.0f/D_);
            __syncthreads();
            float dvv = a3-mb;
            if (tid<D_) red[tid] = dvv*dvv;
            __syncthreads();
            for (int sh=64;sh;sh>>=1){ if(tid<sh) red[tid]+=red[tid+sh]; __syncthreads(); }
            float vb = red[0]*(1.0f/D_);
            if (tid<D_) bcast[b*D_+tid] = dvv*(1.0f/sqrtf(vb+1e-5f))*wln_g[tid]+wln_b[tid];
        }
        __syncthreads();
    }
    if (tid < S_*D_) states[b*N_*D_ + tid] = st[tid];   // only nodes 0..7 changed
}

// -------------------- QKV projections, one block per (b,n) --------------------
__global__ void k_qkv(const float* __restrict__ states,
        const float* __restrict__ cq_w, const float* __restrict__ cq_b,
        const float* __restrict__ ck_w, const float* __restrict__ ck_b,
        const float* __restrict__ cv_w, const float* __restrict__ cv_b,
        float* __restrict__ Q, float* __restrict__ K, float* __restrict__ Vv){
    int blk = blockIdx.x; int b = blk>>5, n = blk&31;
    int d = threadIdx.x;
    __shared__ float sc[D_];
    int base = (b*N_+n)*D_;
    sc[d] = states[base+d];
    __syncthreads();
    float aq=cq_b[d], ak=ck_b[d], av=cv_b[d];
    #pragma unroll 4
    for (int k=0;k<D_;k++){
        float x = sc[k];
        aq += x*cq_w[k*D_+d];
        ak += x*ck_w[k*D_+d];
        av += x*cv_w[k*D_+d];
    }
    Q[base+d]=aq; K[base+d]=ak; Vv[base+d]=av;
}

// -------------------- comm attention + co + LN --------------------
#define KS 129
__global__ void k_attn(const float* __restrict__ states,
        const float* __restrict__ Qg, const float* __restrict__ Kg, const float* __restrict__ Vg,
        const float* __restrict__ co_w, const float* __restrict__ co_b,
        const float* __restrict__ cln_g, const float* __restrict__ cln_b,
        float* __restrict__ states2){
    int blk = blockIdx.x; int b=blk>>5, n=blk&31;
    int tid = threadIdx.x; // 128
    __shared__ float Kt[N_*KS], Vt[N_*KS];
    __shared__ float q[D_], attw[H_][N_], msg[D_], red[D_];
    for (int i=tid;i<N_*D_;i+=128){
        int m=i>>7, dd=i&127;
        Kt[m*KS+dd]=Kg[(b*N_+m)*D_+dd];
        Vt[m*KS+dd]=Vg[(b*N_+m)*D_+dd];
    }
    q[tid] = Qg[(b*N_+n)*D_+tid];
    __syncthreads();
    {
        int h = tid>>5, m = tid&31;
        float sdot=0;
        #pragma unroll 8
        for (int j=0;j<HD_;j++) sdot += q[h*HD_+j]*Kt[m*KS + h*HD_+j];
        sdot *= 0.17677669529663687f; // 1/sqrt(32)
        float mx = sdot;
        #pragma unroll
        for (int off=16;off;off>>=1) mx = fmaxf(mx, __shfl_xor(mx, off, 32));
        float e = expf(sdot-mx);
        float Z = e;
        #pragma unroll
        for (int off=16;off;off>>=1) Z += __shfl_xor(Z, off, 32);
        attw[h][m] = e/Z;
    }
    __syncthreads();
    {
        int h = tid>>5;
        float mm=0;
        #pragma unroll 4
        for (int m=0;m<N_;m++) mm += attw[h][m]*Vt[m*KS+tid];
        msg[tid]=mm;
    }
    __syncthreads();
    float acc = co_b[tid];
    #pragma unroll 8
    for (int k=0;k<D_;k++) acc += msg[k]*co_w[k*D_+tid];
    float x = states[(b*N_+n)*D_+tid] + acc;
    red[tid]=x; __syncthreads();
    for (int sh=64;sh;sh>>=1){ if(tid<sh) red[tid]+=red[tid+sh]; __syncthreads(); }
    float m_ = red[0]*(1.0f/D_); __syncthreads();
    float dv = x-m_; red[tid]=dv*dv; __syncthreads();
    for (int sh=64;sh;sh>>=1){ if(tid<sh) red[tid]+=red[tid+sh]; __syncthreads(); }
    float var = red[0]*(1.0f/D_);
    states2[(b*N_+n)*D_+tid] = dv*(1.0f/sqrtf(var+1e-5f))*cln_g[tid]+cln_b[tid];
}

// -------------------- per-node brain chain, one block per (b,n) --------------------
__global__ void __launch_bounds__(256) k_brains(int c,
        const float* __restrict__ states2, const float* __restrict__ bcast,
        const float* __restrict__ P_w, const float* __restrict__ P_b,
        const float* __restrict__ D1_w, const float* __restrict__ D1_b,
        const float* __restrict__ D2_w, const float* __restrict__ D2_b,
        const float* __restrict__ G_w, const float* __restrict__ G_b,
        const float* __restrict__ SM_w, const float* __restrict__ SM_b,
        const float* __restrict__ PR_w, const float* __restrict__ PR_b,
        const float* __restrict__ ln_g, const float* __restrict__ ln_b,
        float* __restrict__ states, float* __restrict__ prediction){
    int blk = blockIdx.x;
    // XCD swizzle: node n always lands on XCD n%8 -> each XCD L2 caches 4 nodes' weights
    int x8 = blk & 7, qq = blk >> 3;
    int n = x8 + 8*(qq & 3), b = qq >> 2;
    int tid = threadIdx.x, d = tid & 127, h = tid >> 7;
    __shared__ float pin[3*D_];
    __shared__ float strow[D_];
    __shared__ float part[2][D_];
    __shared__ float din[2*D_];
    __shared__ float gin[2*D_];
    __shared__ float dec[D_], nsv[D_];
    __shared__ float red[256];
    // incoming = mean over nodes of states2
    float inc_p = 0.f;
    for (int m = h*16; m < h*16+16; m++) inc_p += states2[(b*N_+m)*D_+d];
    part[h][d] = inc_p;
    if (h==0) strow[d] = states2[(b*N_+n)*D_+d];
    __syncthreads();
    float inc = (part[0][d]+part[1][d]) * (1.0f/N_);
    float pr = prediction[(b*N_+n)*D_+d];   // previous chunk's prediction
    float diff = inc - pr;
    red[tid] = (h==0)? diff*diff : 0.f;
    __syncthreads();
    for (int sh=128;sh;sh>>=1){ if(tid<sh) red[tid]+=red[tid+sh]; __syncthreads(); }
    float pe = red[0]*(1.0f/D_);
    float surprise = (c>0)? sigm(pe*10.0f) : 0.0f;
    float scale = 1.0f + 0.5f*surprise;
    __syncthreads();
    if (h==0){
        pin[d]      = inc*scale;
        pin[D_+d]   = bcast[b*D_+d];
        pin[2*D_+d] = strow[d];
    }
    __syncthreads();
    // P: K=384 -> perception (gelu) into din[0:128]
    {
        const float* Wn = P_w + ((size_t)n*384 + h*192)*D_ + d;
        float a=0;
        #pragma unroll 4
        for (int k=0;k<192;k++) a += pin[h*192+k]*Wn[(size_t)k*D_];
        __syncthreads();
        part[h][d]=a;
        __syncthreads();
        if (h==0) din[d] = gelu_f(part[0][d]+part[1][d]+P_b[n*D_+d]);
        __syncthreads();
    }
    // SM: K=128 -> self_pred into din[128:256]
    {
        const float* Wn = SM_w + ((size_t)n*128 + h*64)*D_ + d;
        float a=0;
        #pragma unroll 4
        for (int k=0;k<64;k++) a += strow[h*64+k]*Wn[(size_t)k*D_];
        __syncthreads();
        part[h][d]=a;
        __syncthreads();
        if (h==0) din[D_+d] = part[0][d]+part[1][d]+SM_b[n*D_+d];
        __syncthreads();
    }
    // D1: K=256 -> h1 (gelu) into pin[0:128] (reuse)
    {
        const float* Wn = D1_w + ((size_t)n*256 + h*128)*D_ + d;
        float a=0;
        #pragma unroll 4
        for (int k=0;k<128;k++) a += din[h*128+k]*Wn[(size_t)k*D_];
        __syncthreads();
        part[h][d]=a;
        __syncthreads();
        if (h==0) pin[d] = gelu_f(part[0][d]+part[1][d]+D1_b[n*D_+d]);
        __syncthreads();
    }
    // D2: K=128 -> decision
    {
        const float* Wn = D2_w + ((size_t)n*128 + h*64)*D_ + d;
        float a=0;
        #pragma unroll 4
        for (int k=0;k<64;k++) a += pin[h*64+k]*Wn[(size_t)k*D_];
        __syncthreads();
        part[h][d]=a;
        __syncthreads();
        if (h==0){ float v = part[0][d]+part[1][d]+D2_b[n*D_+d]; dec[d]=v; gin[d]=strow[d]; gin[D_+d]=v; }
        __syncthreads();
    }
    // G: K=256 -> gate
    {
        const float* Wn = G_w + ((size_t)n*256 + h*128)*D_ + d;
        float a=0;
        #pragma unroll 4
        for (int k=0;k<128;k++) a += gin[h*128+k]*Wn[(size_t)k*D_];
        __syncthreads();
        part[h][d]=a;
        __syncthreads();
    }
    // new_states = LN(g*dec + (1-g)*states')
    float g=0.f, pre=0.f;
    if (h==0){
        g = sigm(part[0][d]+part[1][d]+G_b[n*D_+d]);
        pre = g*dec[d] + (1.0f-g)*strow[d];
    }
    red[tid] = (h==0)? pre : 0.f;
    __syncthreads();
    for (int sh=128;sh;sh>>=1){ if(tid<sh) red[tid]+=red[tid+sh]; __syncthreads(); }
    float mn = red[0]*(1.0f/D_);
    __syncthreads();
    float dv2 = pre-mn;
    red[tid] = (h==0)? dv2*dv2 : 0.f;
    __syncthreads();
    for (int sh=128;sh;sh>>=1){ if(tid<sh) red[tid]+=red[tid+sh]; __syncthreads(); }
    float var = red[0]*(1.0f/D_);
    __syncthreads();
    if (h==0){
        float nv = dv2*(1.0f/sqrtf(var+1e-5f))*ln_g[d]+ln_b[d];
        nsv[d]=nv;
        states[(b*N_+n)*D_+d]=nv;
    }
    __syncthreads();
    // PR: K=128 -> prediction
    {
        const float* Wn = PR_w + ((size_t)n*128 + h*64)*D_ + d;
        float a=0;
        #pragma unroll 4
        for (int k=0;k<64;k++) a += nsv[h*64+k]*Wn[(size_t)k*D_];
        __syncthreads();
        part[h][d]=a;
        __syncthreads();
        if (h==0) prediction[(b*N_+n)*D_+d] = part[0][d]+part[1][d]+PR_b[n*D_+d];
    }
}

// -------------------- f32 -> bf16 --------------------
__global__ void k_tobf16(const float* __restrict__ src, __hip_bfloat16* __restrict__ dst, int nelem){
    int i = blockIdx.x*256 + threadIdx.x;
    int stride = gridDim.x*256;
    for (; i<nelem; i+=stride) dst[i] = __float2bfloat16(src[i]);
}

// -------------------- final logits GEMM: (2048x128) @ (128x32000) + bias --------------------
typedef __attribute__((ext_vector_type(8))) short short8;
typedef __attribute__((ext_vector_type(4))) float f32x4;

__global__ void __launch_bounds__(256) k_gemm(const __hip_bfloat16* __restrict__ A,  // proj bf16, M x 128
                       const __hip_bfloat16* __restrict__ Bv,                        // emb bf16, V x 128
                       const float* __restrict__ out_bias,
                       float* __restrict__ out){
    int vblk = blockIdx.x;   // 125 blocks * 256 v
    int mblk = blockIdx.y;   // 32 blocks * 64 m
    int tid = threadIdx.x;
    int wave = tid >> 6, lane = tid & 63;
    int l16 = lane & 15, quad = lane >> 4;
    int mrow = mblk*64 + wave*16 + l16;       // A-frag row (m = lane&15)
    f32x4 acc[16];
    #pragma unroll
    for (int j=0;j<16;j++){ f32x4 z = {0.f,0.f,0.f,0.f}; acc[j]=z; }
    short8 afr[4];
    const short* Ap = reinterpret_cast<const short*>(A);
    #pragma unroll
    for (int ks=0;ks<4;ks++)
        afr[ks] = *reinterpret_cast<const short8*>(Ap + mrow*128 + ks*32 + quad*8);
    const short* Bp = reinterpret_cast<const short*>(Bv);
    int vcolbase = vblk*256;
    #pragma unroll
    for (int jj=0;jj<16;jj++){
        int v = vcolbase + jj*16 + l16;      // B-frag col (n = lane&15)
        #pragma unroll
        for (int ks=0;ks<4;ks++){
            short8 bfr = *reinterpret_cast<const short8*>(Bp + (size_t)v*128 + ks*32 + quad*8);
            acc[jj] = __builtin_amdgcn_mfma_f32_16x16x32_bf16(afr[ks], bfr, acc[jj], 0,0,0);
        }
    }
    int mbase = mblk*64 + wave*16 + quad*4;  // C/D: row = quad*4 + reg, col = lane&15
    #pragma unroll
    for (int jj=0;jj<16;jj++){
        int v = vcolbase + jj*16 + l16;
        float bias = out_bias[v];
        #pragma unroll
        for (int r=0;r<4;r++){
            out[(size_t)(mbase+r)*V_ + v] = acc[jj][r] + bias;
        }
    }
}

extern "C" void kernel_launch(void* const* d_in, const int* in_sizes, int n_in,
                              void* d_out, int out_size, void* d_ws, size_t ws_size,
                              hipStream_t stream){
    (void)in_sizes; (void)n_in; (void)out_size; (void)ws_size;
    const int*   idx      = (const int*)  d_in[0];
    const float* emb      = (const float*)d_in[1];
    const float* pos_emb  = (const float*)d_in[2];
    const float* ifc_w    = (const float*)d_in[3];
    const float* ifc_b    = (const float*)d_in[4];
    const float* ifc_g    = (const float*)d_in[5];
    const float* ifc_beta = (const float*)d_in[6];
    const float* sproj_w  = (const float*)d_in[7];
    const float* sproj_b  = (const float*)d_in[8];
    const float* sgate_w  = (const float*)d_in[9];
    const float* sgate_b  = (const float*)d_in[10];
    const float* P_w  = (const float*)d_in[11];
    const float* P_b  = (const float*)d_in[12];
    const float* D1_w = (const float*)d_in[13];
    const float* D1_b = (const float*)d_in[14];
    const float* D2_w = (const float*)d_in[15];
    const float* D2_b = (const float*)d_in[16];
    // d_in[17], d_in[18]: A_w, A_b -- unused by the reference output
    const float* G_w  = (const float*)d_in[19];
    const float* G_b  = (const float*)d_in[20];
    const float* SM_w = (const float*)d_in[21];
    const float* SM_b = (const float*)d_in[22];
    const float* PR_w = (const float*)d_in[23];
    const float* PR_b = (const float*)d_in[24];
    const float* cq_w = (const float*)d_in[25];
    const float* cq_b = (const float*)d_in[26];
    const float* ck_w = (const float*)d_in[27];
    const float* ck_b = (const float*)d_in[28];
    const float* cv_w = (const float*)d_in[29];
    const float* cv_b = (const float*)d_in[30];
    const float* co_w = (const float*)d_in[31];
    const float* co_b = (const float*)d_in[32];
    const float* cln_g = (const float*)d_in[33];
    const float* cln_b = (const float*)d_in[34];
    const float* sal_w = (const float*)d_in[35];
    const float* sal_b = (const float*)d_in[36];
    const float* bcast_w = (const float*)d_in[37];
    const float* bcast_b = (const float*)d_in[38];
    const float* wln_g = (const float*)d_in[39];
    const float* wln_b = (const float*)d_in[40];
    const float* res_w = (const float*)d_in[41];
    const float* res_b = (const float*)d_in[42];
    const float* out_w = (const float*)d_in[43];
    const float* out_b = (const float*)d_in[44];
    const float* out_bias = (const float*)d_in[45];
    const float* ln_g = (const float*)d_in[46];
    const float* ln_b = (const float*)d_in[47];

    float* ws = (float*)d_ws;
    float* states     = ws + 0;          // 32768
    float* prediction = ws + 32768;      // 32768
    float* states2    = ws + 65536;      // 32768
    float* bcastv     = ws + 98304;      // 1024
    float* Qb         = ws + 99328;      // 32768
    float* Kb         = ws + 132096;     // 32768
    float* Vb         = ws + 164864;     // 32768
    float* percepts   = ws + 197632;     // 262144
    float* sensory    = ws + 459776;     // 2097152
    float* sg_sens    = ws + 2556928;    // 2097152
    float* outresb    = ws + 4654080;    // 262144
    float* projb      = ws + 4916224;    // 262144
    __hip_bfloat16* proj_bf = (__hip_bfloat16*)(ws + 5178368);  // 262144 bf16
    __hip_bfloat16* emb_bf  = (__hip_bfloat16*)(ws + 5309440);  // 4096000 bf16 -> ends at float 7357440 (~28 MB)

    // zero the carried state (states + prediction are contiguous)
    hipMemsetAsync(states, 0, 2*32768*sizeof(float), stream);

    k_tobf16<<<512,256,0,stream>>>(emb, emb_bf, V_*D_);
    k_percepts<<<B_*T_,128,0,stream>>>(idx, emb, pos_emb, ifc_w, ifc_b, ifc_g, ifc_beta, percepts);
    k_precomp<<<256,256,0,stream>>>(percepts, sproj_w, sproj_b, sgate_w, res_w, res_b, out_w,
                                    sensory, sg_sens, outresb);
    for (int c=0;c<NCHUNK;c++){
        k_scan<<<B_,1024,0,stream>>>(c, sensory, sg_sens, sgate_w, sgate_b, sal_w, sal_b,
                                     out_w, out_b, outresb, bcast_w, bcast_b, wln_g, wln_b,
                                     states, bcastv, projb);
        k_qkv<<<256,128,0,stream>>>(states, cq_w,cq_b,ck_w,ck_b,cv_w,cv_b, Qb,Kb,Vb);
        k_attn<<<256,128,0,stream>>>(states, Qb,Kb,Vb, co_w,co_b, cln_g,cln_b, states2);
        k_brains<<<256,256,0,stream>>>(c, states2, bcastv, P_w,P_b,D1_w,D1_b,D2_w,D2_b,
                                       G_w,G_b,SM_w,SM_b,PR_w,PR_b, ln_g,ln_b,
                                       states, prediction);
    }
    k_tobf16<<<256,256,0,stream>>>(projb, proj_bf, B_*T_*D_);
    k_gemm<<<dim3(125,32),256,0,stream>>>(proj_bf, emb_bf, out_bias, (float*)d_out);
}